// Round 2
// baseline (375.659 us; speedup 1.0000x reference)
//
#include <hip/hip_runtime.h>

#define NF_   2
#define NLOC_ 2048
#define NALL_ 3072
#define NNEI_ 128
#define H_    8
#define D_    32
#define CH_   256   // H*D == Q_DIM

// ---------------------------------------------------------------------------
// fp32 GEMM tile: C[M,256] = A[M,256] @ W[256,256]^T (+ epilogue)
// BM=128, BN=128, BK=16, 256 threads, 8x8 micro-tile per thread.
// LDS traffic: 64 B per 64 FLOP per thread (1 B/FLOP).
// mode: 0 = *norm (qh), 1 = sigmoid(x + bvec[col]) (gate), 2 = none, 3 = +bvec[col]
// ---------------------------------------------------------------------------
__device__ __forceinline__ void gemm128x128(
    const float* __restrict__ A, const float* __restrict__ W,
    const float* __restrict__ bvec, float* __restrict__ C,
    int M, int mode, float (*As)[132], float (*Bs)[132]) {
  const int t  = threadIdx.x;
  const int m0 = blockIdx.y * 128;
  if (m0 >= M) return;
  const int n0 = blockIdx.x * 128;
  const int tx = t & 15;        // 16 col-groups of 8
  const int ty = t >> 4;        // 16 row-groups of 8

  float acc[8][8] = {};

  const int lrow = t >> 1;          // 0..127
  const int lk   = (t & 1) * 8;     // 0 or 8

  for (int k0 = 0; k0 < 256; k0 += 16) {
    const float4 a0 = *(const float4*)(A + (size_t)(m0 + lrow) * 256 + k0 + lk);
    const float4 a1 = *(const float4*)(A + (size_t)(m0 + lrow) * 256 + k0 + lk + 4);
    const float4 w0 = *(const float4*)(W + (size_t)(n0 + lrow) * 256 + k0 + lk);
    const float4 w1 = *(const float4*)(W + (size_t)(n0 + lrow) * 256 + k0 + lk + 4);
    As[lk + 0][lrow] = a0.x; As[lk + 1][lrow] = a0.y;
    As[lk + 2][lrow] = a0.z; As[lk + 3][lrow] = a0.w;
    As[lk + 4][lrow] = a1.x; As[lk + 5][lrow] = a1.y;
    As[lk + 6][lrow] = a1.z; As[lk + 7][lrow] = a1.w;
    Bs[lk + 0][lrow] = w0.x; Bs[lk + 1][lrow] = w0.y;
    Bs[lk + 2][lrow] = w0.z; Bs[lk + 3][lrow] = w0.w;
    Bs[lk + 4][lrow] = w1.x; Bs[lk + 5][lrow] = w1.y;
    Bs[lk + 6][lrow] = w1.z; Bs[lk + 7][lrow] = w1.w;
    __syncthreads();
#pragma unroll
    for (int kk = 0; kk < 16; ++kk) {
      const float4 av0 = *(const float4*)(&As[kk][ty * 8]);
      const float4 av1 = *(const float4*)(&As[kk][ty * 8 + 4]);
      const float4 bv0 = *(const float4*)(&Bs[kk][tx * 8]);
      const float4 bv1 = *(const float4*)(&Bs[kk][tx * 8 + 4]);
      const float a[8] = {av0.x, av0.y, av0.z, av0.w, av1.x, av1.y, av1.z, av1.w};
      const float b[8] = {bv0.x, bv0.y, bv0.z, bv0.w, bv1.x, bv1.y, bv1.z, bv1.w};
#pragma unroll
      for (int i = 0; i < 8; ++i)
#pragma unroll
        for (int j = 0; j < 8; ++j) acc[i][j] = fmaf(a[i], b[j], acc[i][j]);
    }
    __syncthreads();
  }

  const float norm = 0.17677669529663687f;  // 1/sqrt(32)
#pragma unroll
  for (int i = 0; i < 8; ++i) {
    const int row = m0 + ty * 8 + i;
#pragma unroll
    for (int jj = 0; jj < 2; ++jj) {
      float4 o;
      float* op = (float*)&o;
#pragma unroll
      for (int j = 0; j < 4; ++j) {
        const int col = n0 + tx * 8 + jj * 4 + j;
        float v = acc[i][jj * 4 + j];
        if (mode == 0)      v *= norm;
        else if (mode == 1) v = 1.f / (1.f + __expf(-(v + bvec[col])));
        else if (mode == 3) v += bvec[col];
        op[j] = v;
      }
      *(float4*)(C + (size_t)row * 256 + n0 + tx * 8 + jj * 4) = o;
    }
  }
}

__global__ __launch_bounds__(256) void proj_kernel(
    const float* __restrict__ q, const float* __restrict__ k, const float* __restrict__ v,
    const float* __restrict__ Wq, const float* __restrict__ Wg,
    const float* __restrict__ Wk, const float* __restrict__ Wv,
    const float* __restrict__ bg,
    float* __restrict__ qh, float* __restrict__ gs,
    float* __restrict__ kh, float* __restrict__ vh) {
  __shared__ float As[16][132];
  __shared__ float Bs[16][132];
  switch (blockIdx.z) {
    case 0:  gemm128x128(q, Wq, nullptr, qh, NF_ * NLOC_, 0, As, Bs); break;
    case 1:  gemm128x128(q, Wg, bg,      gs, NF_ * NLOC_, 1, As, Bs); break;
    case 2:  gemm128x128(k, Wk, nullptr, kh, NF_ * NALL_, 2, As, Bs); break;
    default: gemm128x128(v, Wv, nullptr, vh, NF_ * NALL_, 2, As, Bs); break;
  }
}

__global__ __launch_bounds__(256) void out_gemm_kernel(
    const float* __restrict__ x, const float* __restrict__ Wo,
    const float* __restrict__ bo, float* __restrict__ out) {
  __shared__ float As[16][132];
  __shared__ float Bs[16][132];
  gemm128x128(x, Wo, bo, out, NF_ * NLOC_, 3, As, Bs);
}

// ---------------------------------------------------------------------------
// Attention: one block per (f, n) atom. 256 threads (4 waves).
// QK gather is LDS-staged in 32-neighbor chunks with coalesced row loads
// (one wave instruction reads one full 1 KB K row) and register prefetch of
// the next chunk during compute.
// ---------------------------------------------------------------------------
__global__ __launch_bounds__(256) void attn_kernel(
    const float* __restrict__ qh, const float* __restrict__ gs,
    const float* __restrict__ kh, const float* __restrict__ vh,
    const void* __restrict__ nlist, const float* __restrict__ bias,
    float* __restrict__ x) {
  __shared__ float q_s[CH_];
  __shared__ int   jn[NNEI_];
  __shared__ float p[H_][NNEI_ + 4];   // stride 132: bank-even writes
  __shared__ float K_s[32][260];       // 32-neighbor chunk, pad 4 floats

  const int t   = threadIdx.x;
  const int bid = blockIdx.x;        // == f*NLOC + n
  const int f   = bid >> 11;
  const int n   = bid & (NLOC_ - 1);
  const size_t row = (size_t)bid;

  q_s[t] = qh[row * CH_ + t];

  // nlist dtype detection: int64 -> all high 32-bit words are 0
  const int* nl32 = (const int*)nlist;
  int odd_or = 0;
#pragma unroll
  for (int w = 1; w < 16; w += 2) odd_or |= nl32[w];
  if (t < NNEI_) {
    if (odd_or == 0) {
      const long long* nl64 = (const long long*)nlist;
      jn[t] = (int)nl64[row * NNEI_ + t];
    } else {
      jn[t] = nl32[row * NNEI_ + t];
    }
  }
  __syncthreads();

  const int h  = t >> 5;   // head
  const int il = t & 31;   // lane-in-group
  const int w  = t >> 6;   // wave 0..3
  const int l  = t & 63;   // lane-in-wave

  // hoist q fragment for this head into registers
  float4 qv[8];
  {
    const float4* qp = (const float4*)(q_s + h * D_);
#pragma unroll
    for (int i = 0; i < 8; ++i) qv[i] = qp[i];
  }

  const float* kbase = kh + (size_t)f * NALL_ * CH_;
  const float* bb    = bias + (((size_t)f * H_ + h) * NLOC_ + n) * NNEI_;

  // prefetch chunk 0: wave w loads rows w+4u, one full K row per instruction
  float4 R[8];
#pragma unroll
  for (int u = 0; u < 8; ++u) {
    const int j = jn[w + 4 * u];
    R[u] = *(const float4*)(kbase + (size_t)j * CH_ + l * 4);
  }

  float s[4];
#pragma unroll
  for (int c = 0; c < 4; ++c) {
    __syncthreads();  // K_s free (previous chunk's compute done)
#pragma unroll
    for (int u = 0; u < 8; ++u)
      *(float4*)(&K_s[w + 4 * u][l * 4]) = R[u];
    if (c < 3) {
#pragma unroll
      for (int u = 0; u < 8; ++u) {
        const int j = jn[(c + 1) * 32 + w + 4 * u];
        R[u] = *(const float4*)(kbase + (size_t)j * CH_ + l * 4);
      }
    }
    __syncthreads();  // K_s ready
    const float4* kr = (const float4*)(&K_s[il][h * D_]);
    float a = 0.f;
#pragma unroll
    for (int d4 = 0; d4 < 8; ++d4) {
      const float4 kv = kr[d4];
      a = fmaf(qv[d4].x, kv.x, a);
      a = fmaf(qv[d4].y, kv.y, a);
      a = fmaf(qv[d4].z, kv.z, a);
      a = fmaf(qv[d4].w, kv.w, a);
    }
    s[c] = a + bb[c * 32 + il];
  }

  // softmax over 128 values (4 regs x 32 lanes of this head group)
  float m = fmaxf(fmaxf(s[0], s[1]), fmaxf(s[2], s[3]));
#pragma unroll
  for (int off = 16; off >= 1; off >>= 1) m = fmaxf(m, __shfl_xor(m, off));
  float e[4];
  float sum = 0.f;
#pragma unroll
  for (int r = 0; r < 4; ++r) { e[r] = __expf(s[r] - m); sum += e[r]; }
#pragma unroll
  for (int off = 16; off >= 1; off >>= 1) sum += __shfl_xor(sum, off);
  const float inv = 1.f / sum;
#pragma unroll
  for (int r = 0; r < 4; ++r) p[h][il + 32 * r] = e[r] * inv;
  __syncthreads();

  // PV: thread t -> (h, d). For fixed i, the block reads the full vh row
  // coalesced (wave = 256 B contiguous).
  const int d = il;
  const float* vb = vh + (size_t)f * NALL_ * CH_ + h * D_ + d;
  float acc = 0.f;
  for (int i = 0; i < NNEI_; i += 4) {
    const float4 p4 = *(const float4*)(&p[h][i]);
    const int4  j4 = *(const int4*)(&jn[i]);
    acc = fmaf(p4.x, vb[(size_t)j4.x * CH_], acc);
    acc = fmaf(p4.y, vb[(size_t)j4.y * CH_], acc);
    acc = fmaf(p4.z, vb[(size_t)j4.z * CH_], acc);
    acc = fmaf(p4.w, vb[(size_t)j4.w * CH_], acc);
  }

  const float g = gs[row * CH_ + t];
  x[row * CH_ + t] = g * acc;
}

// ---------------------------------------------------------------------------
extern "C" void kernel_launch(void* const* d_in, const int* in_sizes, int n_in,
                              void* d_out, int out_size, void* d_ws, size_t ws_size,
                              hipStream_t stream) {
  const float* q     = (const float*)d_in[0];
  const float* k     = (const float*)d_in[1];
  const float* v     = (const float*)d_in[2];
  const void*  nlist = d_in[3];
  const float* bias  = (const float*)d_in[4];
  const float* Wq    = (const float*)d_in[5];
  const float* Wk    = (const float*)d_in[6];
  const float* Wv    = (const float*)d_in[7];
  const float* Wg    = (const float*)d_in[8];
  const float* bg    = (const float*)d_in[9];
  const float* Wo    = (const float*)d_in[10];
  const float* bo    = (const float*)d_in[11];
  float* out = (float*)d_out;

  float* ws = (float*)d_ws;
  float* qh = ws;                                   // [4096,256]
  float* gs = qh + (size_t)NF_ * NLOC_ * CH_;       // [4096,256]
  float* kh = gs + (size_t)NF_ * NLOC_ * CH_;       // [6144,256]
  float* vh = kh + (size_t)NF_ * NALL_ * CH_;       // [6144,256]
  float* x  = vh + (size_t)NF_ * NALL_ * CH_;       // [4096,256]

  // projections: z = {qh, gate, kh, vh}; N=256 -> 2 col-blocks of 128
  proj_kernel<<<dim3(2, 48, 4), 256, 0, stream>>>(q, k, v, Wq, Wg, Wk, Wv, bg,
                                                  qh, gs, kh, vh);
  // attention + gating
  attn_kernel<<<dim3(NF_ * NLOC_), 256, 0, stream>>>(qh, gs, kh, vh, nlist, bias, x);
  // output projection
  out_gemm_kernel<<<dim3(2, 32), 256, 0, stream>>>(x, Wo, bo, out);
}

// Round 8
// 208.390 us; speedup vs baseline: 1.8027x; 1.8027x over previous
//
#include <hip/hip_runtime.h>

#define NF_   2
#define NLOC_ 2048
#define NALL_ 3072
#define NNEI_ 128
#define H_    8
#define D_    32
#define CH_   256   // H*D == Q_DIM

// ---------------------------------------------------------------------------
// fp32 GEMM: C[M,256] = A[M,256] @ W[256,256]^T (+ epilogue)
// BM=BN=64, BK=32, 256 threads, 4x4 micro-tile (16 acc VGPRs -> no spill).
// mode: 0 = *norm (qh), 1 = sigmoid(x+bvec) (gate), 2 = none, 3 = +bvec
// ---------------------------------------------------------------------------
__device__ __forceinline__ void gemm64(
    const float* __restrict__ A, const float* __restrict__ W,
    const float* __restrict__ bvec, float* __restrict__ C,
    int M, int mode, float (*As)[68], float (*Bs)[68]) {
  const int t  = threadIdx.x;
  const int m0 = blockIdx.y * 64;
  if (m0 >= M) return;
  const int n0 = blockIdx.x * 64;
  const int tx = t & 15;        // 16 col-groups of 4
  const int ty = t >> 4;        // 16 row-groups of 4

  float acc[4][4] = {};

  const int lrow = t >> 2;          // 0..63
  const int lk   = (t & 3) * 8;     // 0,8,16,24

  for (int k0 = 0; k0 < 256; k0 += 32) {
    // issue global loads before the barrier: latency overlaps prev compute
    const float4 a0 = *(const float4*)(A + (size_t)(m0 + lrow) * 256 + k0 + lk);
    const float4 a1 = *(const float4*)(A + (size_t)(m0 + lrow) * 256 + k0 + lk + 4);
    const float4 w0 = *(const float4*)(W + (size_t)(n0 + lrow) * 256 + k0 + lk);
    const float4 w1 = *(const float4*)(W + (size_t)(n0 + lrow) * 256 + k0 + lk + 4);
    __syncthreads();   // previous tile's compute done
    As[lk + 0][lrow] = a0.x; As[lk + 1][lrow] = a0.y;
    As[lk + 2][lrow] = a0.z; As[lk + 3][lrow] = a0.w;
    As[lk + 4][lrow] = a1.x; As[lk + 5][lrow] = a1.y;
    As[lk + 6][lrow] = a1.z; As[lk + 7][lrow] = a1.w;
    Bs[lk + 0][lrow] = w0.x; Bs[lk + 1][lrow] = w0.y;
    Bs[lk + 2][lrow] = w0.z; Bs[lk + 3][lrow] = w0.w;
    Bs[lk + 4][lrow] = w1.x; Bs[lk + 5][lrow] = w1.y;
    Bs[lk + 6][lrow] = w1.z; Bs[lk + 7][lrow] = w1.w;
    __syncthreads();   // tile ready
#pragma unroll
    for (int kk = 0; kk < 32; ++kk) {
      const float4 av = *(const float4*)(&As[kk][ty * 4]);
      const float4 bv = *(const float4*)(&Bs[kk][tx * 4]);
      const float a[4] = {av.x, av.y, av.z, av.w};
      const float b[4] = {bv.x, bv.y, bv.z, bv.w};
#pragma unroll
      for (int i = 0; i < 4; ++i)
#pragma unroll
        for (int j = 0; j < 4; ++j) acc[i][j] = fmaf(a[i], b[j], acc[i][j]);
    }
  }

  const float norm = 0.17677669529663687f;  // 1/sqrt(32)
#pragma unroll
  for (int i = 0; i < 4; ++i) {
    const int row = m0 + ty * 4 + i;
    float4 o;
    float* op = (float*)&o;
#pragma unroll
    for (int j = 0; j < 4; ++j) {
      const int col = n0 + tx * 4 + j;
      float v = acc[i][j];
      if (mode == 0)      v *= norm;
      else if (mode == 1) v = 1.f / (1.f + __expf(-(v + bvec[col])));
      else if (mode == 3) v += bvec[col];
      op[j] = v;
    }
    *(float4*)(C + (size_t)row * 256 + n0 + tx * 4) = o;
  }
}

__global__ __launch_bounds__(256, 4) void proj_kernel(
    const float* __restrict__ q, const float* __restrict__ k, const float* __restrict__ v,
    const float* __restrict__ Wq, const float* __restrict__ Wg,
    const float* __restrict__ Wk, const float* __restrict__ Wv,
    const float* __restrict__ bg,
    float* __restrict__ qh, float* __restrict__ gs,
    float* __restrict__ kh, float* __restrict__ vh) {
  __shared__ float As[32][68];
  __shared__ float Bs[32][68];
  switch (blockIdx.z) {
    case 0:  gemm64(q, Wq, nullptr, qh, NF_ * NLOC_, 0, As, Bs); break;
    case 1:  gemm64(q, Wg, bg,      gs, NF_ * NLOC_, 1, As, Bs); break;
    case 2:  gemm64(k, Wk, nullptr, kh, NF_ * NALL_, 2, As, Bs); break;
    default: gemm64(v, Wv, nullptr, vh, NF_ * NALL_, 2, As, Bs); break;
  }
}

__global__ __launch_bounds__(256, 4) void out_gemm_kernel(
    const float* __restrict__ x, const float* __restrict__ Wo,
    const float* __restrict__ bo, float* __restrict__ out) {
  __shared__ float As[32][68];
  __shared__ float Bs[32][68];
  gemm64(x, Wo, bo, out, NF_ * NLOC_, 3, As, Bs);
}

// ---------------------------------------------------------------------------
// Attention: one block per (f, n) atom. 256 threads (4 waves).
// K gather staged in LDS, 32-neighbor chunks, FULLY UNROLLED chunk loop so
// every local array index is compile-time static (rule #20: runtime-indexed
// locals get demoted to scratch -> the R2 455MB WRITE_SIZE disaster).
// Transient load->swizzled-store staging; score reads use matching XOR
// swizzle on the 16B-granule index.
// ---------------------------------------------------------------------------
__global__ __launch_bounds__(256, 2) void attn_kernel(
    const float* __restrict__ qh, const float* __restrict__ gs,
    const float* __restrict__ kh, const float* __restrict__ vh,
    const void* __restrict__ nlist, const float* __restrict__ bias,
    float* __restrict__ x) {
  __shared__ float q_s[CH_];
  __shared__ int   jn[NNEI_];
  __shared__ float p[H_][NNEI_ + 4];
  __shared__ float K_s[32][256];   // one 32-neighbor chunk, swizzled content

  const int t   = threadIdx.x;
  const int bid = blockIdx.x;        // == f*NLOC + n
  const int f   = bid >> 11;
  const int n   = bid & (NLOC_ - 1);
  const size_t row = (size_t)bid;

  q_s[t] = qh[row * CH_ + t];

  // nlist dtype detection: int64 -> all high 32-bit words are 0
  const int* nl32 = (const int*)nlist;
  int odd_or = 0;
#pragma unroll
  for (int w = 1; w < 16; w += 2) odd_or |= nl32[w];
  if (t < NNEI_) {
    if (odd_or == 0) {
      const long long* nl64 = (const long long*)nlist;
      jn[t] = (int)nl64[row * NNEI_ + t];
    } else {
      jn[t] = nl32[row * NNEI_ + t];
    }
  }
  __syncthreads();

  const int h  = t >> 5;   // head
  const int il = t & 31;   // lane-in-group
  const int w  = t >> 6;   // wave 0..3
  const int l  = t & 63;   // lane-in-wave

  // q fragment for this head -> registers
  float4 qv[8];
  {
    const float4* qp = (const float4*)(q_s + h * D_);
#pragma unroll
    for (int i = 0; i < 8; ++i) qv[i] = qp[i];
  }

  const float* kbase = kh + (size_t)f * NALL_ * CH_;
  const float* bb    = bias + (((size_t)f * H_ + h) * NLOC_ + n) * NNEI_;

  float s[4];
#pragma unroll
  for (int c = 0; c < 4; ++c) {     // FULL unroll: s[c] etc. static-indexed
    if (c) __syncthreads();          // previous chunk's compute done
    // stage: wave w loads rows w*8..w*8+7; lane l covers granule l of the
    // 1 KB row (coalesced); store at granule l ^ (r&7)  (XOR swizzle)
#pragma unroll
    for (int u = 0; u < 8; ++u) {
      const int r = w * 8 + u;
      const int j = jn[c * 32 + r];
      const float4 kv = *(const float4*)(kbase + (size_t)j * CH_ + l * 4);
      *(float4*)(&K_s[r][(l ^ (r & 7)) * 4]) = kv;
    }
    __syncthreads();                 // chunk ready
    const int swz = il & 7;
    const float4* krow = (const float4*)(&K_s[il][0]);
    float a = 0.f;
#pragma unroll
    for (int d4 = 0; d4 < 8; ++d4) {
      const float4 kv = krow[(h * 8 + d4) ^ swz];
      a = fmaf(qv[d4].x, kv.x, a);
      a = fmaf(qv[d4].y, kv.y, a);
      a = fmaf(qv[d4].z, kv.z, a);
      a = fmaf(qv[d4].w, kv.w, a);
    }
    s[c] = a + bb[c * 32 + il];
  }

  // softmax over 128 values (4 regs x 32 lanes of this head group)
  float m = fmaxf(fmaxf(s[0], s[1]), fmaxf(s[2], s[3]));
#pragma unroll
  for (int off = 16; off >= 1; off >>= 1) m = fmaxf(m, __shfl_xor(m, off));
  float e[4];
  float sum = 0.f;
#pragma unroll
  for (int r = 0; r < 4; ++r) { e[r] = __expf(s[r] - m); sum += e[r]; }
#pragma unroll
  for (int off = 16; off >= 1; off >>= 1) sum += __shfl_xor(sum, off);
  const float inv = 1.f / sum;
#pragma unroll
  for (int r = 0; r < 4; ++r) p[h][il + 32 * r] = e[r] * inv;
  __syncthreads();

  // PV: thread t -> (h, d). For fixed i the block reads the full vh row
  // coalesced; 4 independent accumulators break the FMA chain.
  // (no forced unroll: compiler picks depth; R1 ran this at VGPR=36, no spill)
  const float* vb = vh + (size_t)f * NALL_ * CH_ + h * D_ + il;
  float ac0 = 0.f, ac1 = 0.f, ac2 = 0.f, ac3 = 0.f;
  for (int i = 0; i < NNEI_; i += 4) {
    const float4 p4 = *(const float4*)(&p[h][i]);
    const int4  j4 = *(const int4*)(&jn[i]);
    ac0 = fmaf(p4.x, vb[(size_t)j4.x * CH_], ac0);
    ac1 = fmaf(p4.y, vb[(size_t)j4.y * CH_], ac1);
    ac2 = fmaf(p4.z, vb[(size_t)j4.z * CH_], ac2);
    ac3 = fmaf(p4.w, vb[(size_t)j4.w * CH_], ac3);
  }
  const float acc = (ac0 + ac1) + (ac2 + ac3);

  const float g = gs[row * CH_ + t];
  x[row * CH_ + t] = g * acc;
}

// ---------------------------------------------------------------------------
extern "C" void kernel_launch(void* const* d_in, const int* in_sizes, int n_in,
                              void* d_out, int out_size, void* d_ws, size_t ws_size,
                              hipStream_t stream) {
  const float* q     = (const float*)d_in[0];
  const float* k     = (const float*)d_in[1];
  const float* v     = (const float*)d_in[2];
  const void*  nlist = d_in[3];
  const float* bias  = (const float*)d_in[4];
  const float* Wq    = (const float*)d_in[5];
  const float* Wk    = (const float*)d_in[6];
  const float* Wv    = (const float*)d_in[7];
  const float* Wg    = (const float*)d_in[8];
  const float* bg    = (const float*)d_in[9];
  const float* Wo    = (const float*)d_in[10];
  const float* bo    = (const float*)d_in[11];
  float* out = (float*)d_out;

  float* ws = (float*)d_ws;
  float* qh = ws;                                   // [4096,256]
  float* gs = qh + (size_t)NF_ * NLOC_ * CH_;       // [4096,256]
  float* kh = gs + (size_t)NF_ * NLOC_ * CH_;       // [6144,256]
  float* vh = kh + (size_t)NF_ * NALL_ * CH_;       // [6144,256]
  float* x  = vh + (size_t)NF_ * NALL_ * CH_;       // [4096,256]

  // projections: z = {qh, gate, kh, vh}; 64x64 tiles
  proj_kernel<<<dim3(4, 96, 4), 256, 0, stream>>>(q, k, v, Wq, Wg, Wk, Wv, bg,
                                                  qh, gs, kh, vh);
  // attention + gating
  attn_kernel<<<dim3(NF_ * NLOC_), 256, 0, stream>>>(qh, gs, kh, vh, nlist, bias, x);
  // output projection
  out_gemm_kernel<<<dim3(4, 64), 256, 0, stream>>>(x, Wo, bo, out);
}

// Round 10
// 190.573 us; speedup vs baseline: 1.9712x; 1.0935x over previous
//
#include <hip/hip_runtime.h>

#define NF_   2
#define NLOC_ 2048
#define NALL_ 3072
#define NNEI_ 128
#define H_    8
#define D_    32
#define CH_   256   // H*D == Q_DIM

typedef __attribute__((ext_vector_type(8))) short  short8v;   // mfma bf16x8 operand
typedef __attribute__((ext_vector_type(8))) unsigned short ushort8v;
typedef __attribute__((ext_vector_type(4))) float  floatx4;   // mfma f32x4 acc

// fp32 -> bf16 RNE, and back
__device__ __forceinline__ unsigned short f2bf(float x) {
  unsigned u = __float_as_uint(x);
  unsigned r = u + 0x7fff + ((u >> 16) & 1);
  return (unsigned short)(r >> 16);
}
__device__ __forceinline__ float bf2f(unsigned short h) {
  return __uint_as_float(((unsigned)h) << 16);
}

// convert 8 fp32 (two float4) into hi/lo bf16x8 and store to LDS (b128 x2)
__device__ __forceinline__ void cvt_store(unsigned short* hp, unsigned short* lp,
                                          float4 u, float4 v) {
  ushort8v hv, lv;
  hv[0] = f2bf(u.x); lv[0] = f2bf(u.x - bf2f(hv[0]));
  hv[1] = f2bf(u.y); lv[1] = f2bf(u.y - bf2f(hv[1]));
  hv[2] = f2bf(u.z); lv[2] = f2bf(u.z - bf2f(hv[2]));
  hv[3] = f2bf(u.w); lv[3] = f2bf(u.w - bf2f(hv[3]));
  hv[4] = f2bf(v.x); lv[4] = f2bf(v.x - bf2f(hv[4]));
  hv[5] = f2bf(v.y); lv[5] = f2bf(v.y - bf2f(hv[5]));
  hv[6] = f2bf(v.z); lv[6] = f2bf(v.z - bf2f(hv[6]));
  hv[7] = f2bf(v.w); lv[7] = f2bf(v.w - bf2f(hv[7]));
  *(ushort8v*)hp = hv;
  *(ushort8v*)lp = lv;
}

// ---------------------------------------------------------------------------
// Split-bf16 MFMA GEMM: C[M,256] = A[M,256] @ W[256,256]^T (+ epilogue).
// x = hi + lo (2x bf16, RNE); x*y ~= hi*hi + hi*lo + lo*hi  (drop lo*lo,
// <= 2^-18 relative -> ~4e-6: below fp32-GEMM noise). fp32 MFMA accumulate.
// BM=BN=128, BK=32, 256 threads = 4 waves (2x2), wave tile 64x64 =
// 4x4 frags of 16x16, 48 mfma_f32_16x16x32_bf16 per wave per K-step.
// LDS rows padded to 40 ushort (80 B = 5*16 B: rows stay 16B-aligned,
// bank rotation (20*r)%32 spreads the 16-lane column reads).
// mode: 0 = *norm (qh), 1 = sigmoid(x+bvec) (gate), 2 = none, 3 = +bvec
// ---------------------------------------------------------------------------
__device__ __forceinline__ void gemm_mfma(
    const float* __restrict__ A, const float* __restrict__ W,
    const float* __restrict__ bvec, float* __restrict__ C,
    int M, int mode,
    unsigned short (*Ah)[40], unsigned short (*Al)[40],
    unsigned short (*Wh)[40], unsigned short (*Wl)[40]) {
  const int t  = threadIdx.x;
  const int m0 = blockIdx.y * 128;
  if (m0 >= M) return;
  const int n0 = blockIdx.x * 128;

  const int lane = t & 63;
  const int wv   = t >> 6;        // wave 0..3
  const int wr   = wv >> 1;       // wave row 0..1 (M)
  const int wc   = wv & 1;        // wave col 0..1 (N)
  const int l15  = lane & 15;
  const int ko   = (lane >> 4) * 8;   // k-offset of this lane's fragment

  // staging assignment: thread covers row r = t>>1 (0..127), k-half (t&1)*16
  const int sr = t >> 1;
  const int sk = (t & 1) * 16;

  floatx4 acc[4][4] = {};

  for (int k0 = 0; k0 < 256; k0 += 32) {
    // issue global loads first: latency overlaps previous K-step's MFMAs
    const float* Ap = A + (size_t)(m0 + sr) * 256 + k0 + sk;
    const float* Wp = W + (size_t)(n0 + sr) * 256 + k0 + sk;
    const float4 a0 = *(const float4*)(Ap + 0);
    const float4 a1 = *(const float4*)(Ap + 4);
    const float4 a2 = *(const float4*)(Ap + 8);
    const float4 a3 = *(const float4*)(Ap + 12);
    const float4 w0 = *(const float4*)(Wp + 0);
    const float4 w1 = *(const float4*)(Wp + 4);
    const float4 w2 = *(const float4*)(Wp + 8);
    const float4 w3 = *(const float4*)(Wp + 12);
    __syncthreads();   // previous K-step's LDS reads done
    cvt_store(&Ah[sr][sk + 0], &Al[sr][sk + 0], a0, a1);
    cvt_store(&Ah[sr][sk + 8], &Al[sr][sk + 8], a2, a3);
    cvt_store(&Wh[sr][sk + 0], &Wl[sr][sk + 0], w0, w1);
    cvt_store(&Wh[sr][sk + 8], &Wl[sr][sk + 8], w2, w3);
    __syncthreads();   // tile ready

    short8v afh[4], afl[4], bfh[4], bfl[4];
#pragma unroll
    for (int mi = 0; mi < 4; ++mi) {
      const int rr = wr * 64 + mi * 16 + l15;
      afh[mi] = *(const short8v*)&Ah[rr][ko];
      afl[mi] = *(const short8v*)&Al[rr][ko];
    }
#pragma unroll
    for (int ni = 0; ni < 4; ++ni) {
      const int rr = wc * 64 + ni * 16 + l15;
      bfh[ni] = *(const short8v*)&Wh[rr][ko];
      bfl[ni] = *(const short8v*)&Wl[rr][ko];
    }
#pragma unroll
    for (int mi = 0; mi < 4; ++mi)
#pragma unroll
      for (int ni = 0; ni < 4; ++ni) {
        acc[mi][ni] = __builtin_amdgcn_mfma_f32_16x16x32_bf16(
            afh[mi], bfh[ni], acc[mi][ni], 0, 0, 0);
        acc[mi][ni] = __builtin_amdgcn_mfma_f32_16x16x32_bf16(
            afh[mi], bfl[ni], acc[mi][ni], 0, 0, 0);
        acc[mi][ni] = __builtin_amdgcn_mfma_f32_16x16x32_bf16(
            afl[mi], bfh[ni], acc[mi][ni], 0, 0, 0);
      }
  }

  // epilogue: D layout col = lane&15, row = (lane>>4)*4 + r   [m89-verified]
  const float norm = 0.17677669529663687f;  // 1/sqrt(32)
#pragma unroll
  for (int mi = 0; mi < 4; ++mi)
#pragma unroll
    for (int ni = 0; ni < 4; ++ni) {
      const int col = n0 + wc * 64 + ni * 16 + l15;
      const float bv = (mode == 1 || mode == 3) ? bvec[col] : 0.f;
#pragma unroll
      for (int r = 0; r < 4; ++r) {
        const int row = m0 + wr * 64 + mi * 16 + (lane >> 4) * 4 + r;
        float vv = acc[mi][ni][r];
        if (mode == 0)      vv *= norm;
        else if (mode == 1) vv = 1.f / (1.f + __expf(-(vv + bv)));
        else if (mode == 3) vv += bv;
        C[(size_t)row * 256 + col] = vv;
      }
    }
}

__global__ __launch_bounds__(256, 2) void proj_kernel(
    const float* __restrict__ q, const float* __restrict__ k, const float* __restrict__ v,
    const float* __restrict__ Wq, const float* __restrict__ Wg,
    const float* __restrict__ Wk, const float* __restrict__ Wv,
    const float* __restrict__ bg,
    float* __restrict__ qh, float* __restrict__ gs,
    float* __restrict__ kh, float* __restrict__ vh) {
  __shared__ unsigned short Ah[128][40], Al[128][40], Wh[128][40], Wl[128][40];
  switch (blockIdx.z) {
    case 0:  gemm_mfma(q, Wq, nullptr, qh, NF_ * NLOC_, 0, Ah, Al, Wh, Wl); break;
    case 1:  gemm_mfma(q, Wg, bg,      gs, NF_ * NLOC_, 1, Ah, Al, Wh, Wl); break;
    case 2:  gemm_mfma(k, Wk, nullptr, kh, NF_ * NALL_, 2, Ah, Al, Wh, Wl); break;
    default: gemm_mfma(v, Wv, nullptr, vh, NF_ * NALL_, 2, Ah, Al, Wh, Wl); break;
  }
}

__global__ __launch_bounds__(256, 2) void out_gemm_kernel(
    const float* __restrict__ x, const float* __restrict__ Wo,
    const float* __restrict__ bo, float* __restrict__ out) {
  __shared__ unsigned short Ah[128][40], Al[128][40], Wh[128][40], Wl[128][40];
  gemm_mfma(x, Wo, bo, out, NF_ * NLOC_, 3, Ah, Al, Wh, Wl);
}

// ---------------------------------------------------------------------------
// Attention: one block per (f, n) atom. 256 threads (4 waves).
// (UNCHANGED from the 72 us measured version.)
// ---------------------------------------------------------------------------
__global__ __launch_bounds__(256, 2) void attn_kernel(
    const float* __restrict__ qh, const float* __restrict__ gs,
    const float* __restrict__ kh, const float* __restrict__ vh,
    const void* __restrict__ nlist, const float* __restrict__ bias,
    float* __restrict__ x) {
  __shared__ float q_s[CH_];
  __shared__ int   jn[NNEI_];
  __shared__ float p[H_][NNEI_ + 4];
  __shared__ float K_s[32][256];   // one 32-neighbor chunk, swizzled content

  const int t   = threadIdx.x;
  const int bid = blockIdx.x;        // == f*NLOC + n
  const int f   = bid >> 11;
  const int n   = bid & (NLOC_ - 1);
  const size_t row = (size_t)bid;

  q_s[t] = qh[row * CH_ + t];

  // nlist dtype detection: int64 -> all high 32-bit words are 0
  const int* nl32 = (const int*)nlist;
  int odd_or = 0;
#pragma unroll
  for (int w = 1; w < 16; w += 2) odd_or |= nl32[w];
  if (t < NNEI_) {
    if (odd_or == 0) {
      const long long* nl64 = (const long long*)nlist;
      jn[t] = (int)nl64[row * NNEI_ + t];
    } else {
      jn[t] = nl32[row * NNEI_ + t];
    }
  }
  __syncthreads();

  const int h  = t >> 5;   // head
  const int il = t & 31;   // lane-in-group
  const int w  = t >> 6;   // wave 0..3
  const int l  = t & 63;   // lane-in-wave

  // q fragment for this head -> registers
  float4 qv[8];
  {
    const float4* qp = (const float4*)(q_s + h * D_);
#pragma unroll
    for (int i = 0; i < 8; ++i) qv[i] = qp[i];
  }

  const float* kbase = kh + (size_t)f * NALL_ * CH_;
  const float* bb    = bias + (((size_t)f * H_ + h) * NLOC_ + n) * NNEI_;

  float s[4];
#pragma unroll
  for (int c = 0; c < 4; ++c) {     // FULL unroll: s[c] etc. static-indexed
    if (c) __syncthreads();          // previous chunk's compute done
    // stage: wave w loads rows w*8..w*8+7; lane l covers granule l of the
    // 1 KB row (coalesced); store at granule l ^ (r&7)  (XOR swizzle)
#pragma unroll
    for (int u = 0; u < 8; ++u) {
      const int r = w * 8 + u;
      const int j = jn[c * 32 + r];
      const float4 kv = *(const float4*)(kbase + (size_t)j * CH_ + l * 4);
      *(float4*)(&K_s[r][(l ^ (r & 7)) * 4]) = kv;
    }
    __syncthreads();                 // chunk ready
    const int swz = il & 7;
    const float4* krow = (const float4*)(&K_s[il][0]);
    float a = 0.f;
#pragma unroll
    for (int d4 = 0; d4 < 8; ++d4) {
      const float4 kv = krow[(h * 8 + d4) ^ swz];
      a = fmaf(qv[d4].x, kv.x, a);
      a = fmaf(qv[d4].y, kv.y, a);
      a = fmaf(qv[d4].z, kv.z, a);
      a = fmaf(qv[d4].w, kv.w, a);
    }
    s[c] = a + bb[c * 32 + il];
  }

  // softmax over 128 values (4 regs x 32 lanes of this head group)
  float m = fmaxf(fmaxf(s[0], s[1]), fmaxf(s[2], s[3]));
#pragma unroll
  for (int off = 16; off >= 1; off >>= 1) m = fmaxf(m, __shfl_xor(m, off));
  float e[4];
  float sum = 0.f;
#pragma unroll
  for (int r = 0; r < 4; ++r) { e[r] = __expf(s[r] - m); sum += e[r]; }
#pragma unroll
  for (int off = 16; off >= 1; off >>= 1) sum += __shfl_xor(sum, off);
  const float inv = 1.f / sum;
#pragma unroll
  for (int r = 0; r < 4; ++r) p[h][il + 32 * r] = e[r] * inv;
  __syncthreads();

  // PV: thread t -> (h, d). For fixed i the block reads the full vh row
  // coalesced; 4 independent accumulators break the FMA chain.
  const float* vb = vh + (size_t)f * NALL_ * CH_ + h * D_ + il;
  float ac0 = 0.f, ac1 = 0.f, ac2 = 0.f, ac3 = 0.f;
  for (int i = 0; i < NNEI_; i += 4) {
    const float4 p4 = *(const float4*)(&p[h][i]);
    const int4  j4 = *(const int4*)(&jn[i]);
    ac0 = fmaf(p4.x, vb[(size_t)j4.x * CH_], ac0);
    ac1 = fmaf(p4.y, vb[(size_t)j4.y * CH_], ac1);
    ac2 = fmaf(p4.z, vb[(size_t)j4.z * CH_], ac2);
    ac3 = fmaf(p4.w, vb[(size_t)j4.w * CH_], ac3);
  }
  const float acc = (ac0 + ac1) + (ac2 + ac3);

  const float g = gs[row * CH_ + t];
  x[row * CH_ + t] = g * acc;
}

// ---------------------------------------------------------------------------
extern "C" void kernel_launch(void* const* d_in, const int* in_sizes, int n_in,
                              void* d_out, int out_size, void* d_ws, size_t ws_size,
                              hipStream_t stream) {
  const float* q     = (const float*)d_in[0];
  const float* k     = (const float*)d_in[1];
  const float* v     = (const float*)d_in[2];
  const void*  nlist = d_in[3];
  const float* bias  = (const float*)d_in[4];
  const float* Wq    = (const float*)d_in[5];
  const float* Wk    = (const float*)d_in[6];
  const float* Wv    = (const float*)d_in[7];
  const float* Wg    = (const float*)d_in[8];
  const float* bg    = (const float*)d_in[9];
  const float* Wo    = (const float*)d_in[10];
  const float* bo    = (const float*)d_in[11];
  float* out = (float*)d_out;

  float* ws = (float*)d_ws;
  float* qh = ws;                                   // [4096,256]
  float* gs = qh + (size_t)NF_ * NLOC_ * CH_;       // [4096,256]
  float* kh = gs + (size_t)NF_ * NLOC_ * CH_;       // [6144,256]
  float* vh = kh + (size_t)NF_ * NALL_ * CH_;       // [6144,256]
  float* x  = vh + (size_t)NF_ * NALL_ * CH_;       // [4096,256]

  // projections: z = {qh, gate, kh, vh}; 128x128 MFMA tiles
  proj_kernel<<<dim3(2, 48, 4), 256, 0, stream>>>(q, k, v, Wq, Wg, Wk, Wv, bg,
                                                  qh, gs, kh, vh);
  // attention + gating
  attn_kernel<<<dim3(NF_ * NLOC_), 256, 0, stream>>>(qh, gs, kh, vh, nlist, bias, x);
  // output projection
  out_gemm_kernel<<<dim3(2, 32), 256, 0, stream>>>(x, Wo, bo, out);
}

// Round 12
// 185.278 us; speedup vs baseline: 2.0275x; 1.0286x over previous
//
#include <hip/hip_runtime.h>

#define NF_   2
#define NLOC_ 2048
#define NALL_ 3072
#define NNEI_ 128
#define H_    8
#define D_    32
#define CH_   256   // H*D == Q_DIM

typedef __attribute__((ext_vector_type(8))) short  short8v;   // mfma bf16x8 operand
typedef __attribute__((ext_vector_type(8))) unsigned short ushort8v;
typedef __attribute__((ext_vector_type(4))) float  floatx4;   // mfma f32x4 acc

// fp32 -> bf16 RNE, and back
__device__ __forceinline__ unsigned short f2bf(float x) {
  unsigned u = __float_as_uint(x);
  unsigned r = u + 0x7fff + ((u >> 16) & 1);
  return (unsigned short)(r >> 16);
}
__device__ __forceinline__ float bf2f(unsigned short h) {
  return __uint_as_float(((unsigned)h) << 16);
}

// convert 8 fp32 (two float4) into hi/lo bf16x8 and store to LDS (b128 x2)
__device__ __forceinline__ void cvt_store(unsigned short* hp, unsigned short* lp,
                                          float4 u, float4 v) {
  ushort8v hv, lv;
  hv[0] = f2bf(u.x); lv[0] = f2bf(u.x - bf2f(hv[0]));
  hv[1] = f2bf(u.y); lv[1] = f2bf(u.y - bf2f(hv[1]));
  hv[2] = f2bf(u.z); lv[2] = f2bf(u.z - bf2f(hv[2]));
  hv[3] = f2bf(u.w); lv[3] = f2bf(u.w - bf2f(hv[3]));
  hv[4] = f2bf(v.x); lv[4] = f2bf(v.x - bf2f(hv[4]));
  hv[5] = f2bf(v.y); lv[5] = f2bf(v.y - bf2f(hv[5]));
  hv[6] = f2bf(v.z); lv[6] = f2bf(v.z - bf2f(hv[6]));
  hv[7] = f2bf(v.w); lv[7] = f2bf(v.w - bf2f(hv[7]));
  *(ushort8v*)hp = hv;
  *(ushort8v*)lp = lv;
}

// ---------------------------------------------------------------------------
// One-time W conversion: fp32 [256,256] -> bf16 hi/lo pair (RNE split).
// dst layout: matrix m at dst + m*2*65536; hi then lo, each 65536 ushort.
// ---------------------------------------------------------------------------
__global__ __launch_bounds__(256) void wcvt_kernel(
    const float* __restrict__ W0, const float* __restrict__ W1,
    const float* __restrict__ W2, const float* __restrict__ W3,
    const float* __restrict__ W4, unsigned short* __restrict__ dst) {
  const float* srcs[5] = {W0, W1, W2, W3, W4};
  const float* s = srcs[blockIdx.y];
  unsigned short* hi = dst + (size_t)blockIdx.y * 2 * 65536;
  unsigned short* lo = hi + 65536;
  const int idx = (blockIdx.x * 256 + threadIdx.x) * 4;
  const float4 v = *(const float4*)(s + idx);
  unsigned short h0 = f2bf(v.x), h1 = f2bf(v.y), h2 = f2bf(v.z), h3 = f2bf(v.w);
  ushort4 hv = {h0, h1, h2, h3};
  ushort4 lv = {f2bf(v.x - bf2f(h0)), f2bf(v.y - bf2f(h1)),
                f2bf(v.z - bf2f(h2)), f2bf(v.w - bf2f(h3))};
  *(ushort4*)(hi + idx) = hv;
  *(ushort4*)(lo + idx) = lv;
}

// ---------------------------------------------------------------------------
// Split-bf16 MFMA GEMM: C[M,256] = A[M,256] @ W[256,256]^T (+ epilogue).
// A converted to hi/lo in-kernel; W pre-converted (bf16 hi/lo in global).
// BM=128, BN=64, BK=32, 256 threads = 4 waves (2x2), wave tile 64x32 =
// 4x2 frags, 24 mfma_f32_16x16x32_bf16 per wave per K-step.
// LDS rows padded to 40 ushort (80 B): 16B-aligned rows, bank rotation.
// mode: 0 = *norm (qh), 1 = sigmoid(x+bvec) (gate), 2 = none, 3 = +bvec
// ---------------------------------------------------------------------------
__device__ __forceinline__ void gemm_mfma(
    const float* __restrict__ A,
    const unsigned short* __restrict__ Whi, const unsigned short* __restrict__ Wlo,
    const float* __restrict__ bvec, float* __restrict__ C,
    int M, int mode,
    unsigned short (*Ah)[40], unsigned short (*Al)[40],
    unsigned short (*Wh)[40], unsigned short (*Wl)[40]) {
  const int t  = threadIdx.x;
  const int m0 = blockIdx.y * 128;
  if (m0 >= M) return;
  const int n0 = blockIdx.x * 64;

  const int lane = t & 63;
  const int wv   = t >> 6;        // wave 0..3
  const int wr   = wv >> 1;       // wave row 0..1 (M, x64)
  const int wc   = wv & 1;        // wave col 0..1 (N, x32)
  const int l15  = lane & 15;
  const int ko   = (lane >> 4) * 8;   // k-offset of this lane's fragment

  // A staging: thread covers row t>>1 (0..127), k-half (t&1)*16
  const int sr = t >> 1;
  const int sk = (t & 1) * 16;
  // W staging: thread covers row t>>2 (0..63), 8-ushort col (t&3)*8
  const int wrow = t >> 2;
  const int wk   = (t & 3) * 8;

  floatx4 acc[4][2] = {};

  for (int k0 = 0; k0 < 256; k0 += 32) {
    // issue all global loads first: latency overlaps previous K-step MFMAs
    const float* Ap = A + (size_t)(m0 + sr) * 256 + k0 + sk;
    const float4 a0 = *(const float4*)(Ap + 0);
    const float4 a1 = *(const float4*)(Ap + 4);
    const float4 a2 = *(const float4*)(Ap + 8);
    const float4 a3 = *(const float4*)(Ap + 12);
    const size_t woff = (size_t)(n0 + wrow) * 256 + k0 + wk;
    const uint4 whv = *(const uint4*)(Whi + woff);
    const uint4 wlv = *(const uint4*)(Wlo + woff);
    __syncthreads();   // previous K-step's LDS reads done
    cvt_store(&Ah[sr][sk + 0], &Al[sr][sk + 0], a0, a1);
    cvt_store(&Ah[sr][sk + 8], &Al[sr][sk + 8], a2, a3);
    *(uint4*)&Wh[wrow][wk] = whv;
    *(uint4*)&Wl[wrow][wk] = wlv;
    __syncthreads();   // tile ready

    short8v afh[4], afl[4], bfh[2], bfl[2];
#pragma unroll
    for (int mi = 0; mi < 4; ++mi) {
      const int rr = wr * 64 + mi * 16 + l15;
      afh[mi] = *(const short8v*)&Ah[rr][ko];
      afl[mi] = *(const short8v*)&Al[rr][ko];
    }
#pragma unroll
    for (int ni = 0; ni < 2; ++ni) {
      const int rr = wc * 32 + ni * 16 + l15;
      bfh[ni] = *(const short8v*)&Wh[rr][ko];
      bfl[ni] = *(const short8v*)&Wl[rr][ko];
    }
#pragma unroll
    for (int mi = 0; mi < 4; ++mi)
#pragma unroll
      for (int ni = 0; ni < 2; ++ni) {
        acc[mi][ni] = __builtin_amdgcn_mfma_f32_16x16x32_bf16(
            afh[mi], bfh[ni], acc[mi][ni], 0, 0, 0);
        acc[mi][ni] = __builtin_amdgcn_mfma_f32_16x16x32_bf16(
            afh[mi], bfl[ni], acc[mi][ni], 0, 0, 0);
        acc[mi][ni] = __builtin_amdgcn_mfma_f32_16x16x32_bf16(
            afl[mi], bfh[ni], acc[mi][ni], 0, 0, 0);
      }
  }

  // epilogue: D layout col = lane&15, row = (lane>>4)*4 + r
  const float norm = 0.17677669529663687f;  // 1/sqrt(32)
#pragma unroll
  for (int mi = 0; mi < 4; ++mi)
#pragma unroll
    for (int ni = 0; ni < 2; ++ni) {
      const int col = n0 + wc * 32 + ni * 16 + l15;
      const float bv = (mode == 1 || mode == 3) ? bvec[col] : 0.f;
#pragma unroll
      for (int r = 0; r < 4; ++r) {
        const int row = m0 + wr * 64 + mi * 16 + (lane >> 4) * 4 + r;
        float vv = acc[mi][ni][r];
        if (mode == 0)      vv *= norm;
        else if (mode == 1) vv = 1.f / (1.f + __expf(-(vv + bv)));
        else if (mode == 3) vv += bv;
        C[(size_t)row * 256 + col] = vv;
      }
    }
}

__global__ __launch_bounds__(256, 3) void proj_kernel(
    const float* __restrict__ q, const float* __restrict__ k, const float* __restrict__ v,
    const unsigned short* __restrict__ whl, const float* __restrict__ bg,
    float* __restrict__ qh, float* __restrict__ gs,
    float* __restrict__ kh, float* __restrict__ vh) {
  __shared__ unsigned short Ah[128][40], Al[128][40], Wh[64][40], Wl[64][40];
  const unsigned short* Whi = whl + (size_t)blockIdx.z * 2 * 65536;
  const unsigned short* Wlo = Whi + 65536;
  switch (blockIdx.z) {
    case 0:  gemm_mfma(q, Whi, Wlo, nullptr, qh, NF_ * NLOC_, 0, Ah, Al, Wh, Wl); break;
    case 1:  gemm_mfma(q, Whi, Wlo, bg,      gs, NF_ * NLOC_, 1, Ah, Al, Wh, Wl); break;
    case 2:  gemm_mfma(k, Whi, Wlo, nullptr, kh, NF_ * NALL_, 2, Ah, Al, Wh, Wl); break;
    default: gemm_mfma(v, Whi, Wlo, nullptr, vh, NF_ * NALL_, 2, Ah, Al, Wh, Wl); break;
  }
}

__global__ __launch_bounds__(256, 3) void out_gemm_kernel(
    const float* __restrict__ x, const unsigned short* __restrict__ whl,
    const float* __restrict__ bo, float* __restrict__ out) {
  __shared__ unsigned short Ah[128][40], Al[128][40], Wh[64][40], Wl[64][40];
  const unsigned short* Whi = whl + (size_t)4 * 2 * 65536;
  const unsigned short* Wlo = Whi + 65536;
  gemm_mfma(x, Whi, Wlo, bo, out, NF_ * NLOC_, 3, Ah, Al, Wh, Wl);
}

// ---------------------------------------------------------------------------
// Attention: one block per (f, n) atom. 256 threads (4 waves).
// Identical to the measured 72 us version EXCEPT __launch_bounds__(256,4):
// LDS 38.9 KB allows 4 blocks/CU; the old (256,2) was the occupancy binder
// (measured OccupancyPercent 28%, latency-bound gathers).
// ---------------------------------------------------------------------------
__global__ __launch_bounds__(256, 4) void attn_kernel(
    const float* __restrict__ qh, const float* __restrict__ gs,
    const float* __restrict__ kh, const float* __restrict__ vh,
    const void* __restrict__ nlist, const float* __restrict__ bias,
    float* __restrict__ x) {
  __shared__ float q_s[CH_];
  __shared__ int   jn[NNEI_];
  __shared__ float p[H_][NNEI_ + 4];
  __shared__ float K_s[32][256];   // one 32-neighbor chunk, swizzled content

  const int t   = threadIdx.x;
  const int bid = blockIdx.x;        // == f*NLOC + n
  const int f   = bid >> 11;
  const int n   = bid & (NLOC_ - 1);
  const size_t row = (size_t)bid;

  q_s[t] = qh[row * CH_ + t];

  // nlist dtype detection: int64 -> all high 32-bit words are 0
  const int* nl32 = (const int*)nlist;
  int odd_or = 0;
#pragma unroll
  for (int w = 1; w < 16; w += 2) odd_or |= nl32[w];
  if (t < NNEI_) {
    if (odd_or == 0) {
      const long long* nl64 = (const long long*)nlist;
      jn[t] = (int)nl64[row * NNEI_ + t];
    } else {
      jn[t] = nl32[row * NNEI_ + t];
    }
  }
  __syncthreads();

  const int h  = t >> 5;   // head
  const int il = t & 31;   // lane-in-group
  const int w  = t >> 6;   // wave 0..3
  const int l  = t & 63;   // lane-in-wave

  // q fragment for this head -> registers
  float4 qv[8];
  {
    const float4* qp = (const float4*)(q_s + h * D_);
#pragma unroll
    for (int i = 0; i < 8; ++i) qv[i] = qp[i];
  }

  const float* kbase = kh + (size_t)f * NALL_ * CH_;
  const float* bb    = bias + (((size_t)f * H_ + h) * NLOC_ + n) * NNEI_;

  float s[4];
#pragma unroll
  for (int c = 0; c < 4; ++c) {     // FULL unroll: s[c] etc. static-indexed
    if (c) __syncthreads();          // previous chunk's compute done
    // stage: wave w loads rows w*8..w*8+7; lane l covers granule l of the
    // 1 KB row (coalesced); store at granule l ^ (r&7)  (XOR swizzle)
#pragma unroll
    for (int u = 0; u < 8; ++u) {
      const int r = w * 8 + u;
      const int j = jn[c * 32 + r];
      const float4 kv = *(const float4*)(kbase + (size_t)j * CH_ + l * 4);
      *(float4*)(&K_s[r][(l ^ (r & 7)) * 4]) = kv;
    }
    __syncthreads();                 // chunk ready
    const int swz = il & 7;
    const float4* krow = (const float4*)(&K_s[il][0]);
    float a = 0.f;
#pragma unroll
    for (int d4 = 0; d4 < 8; ++d4) {
      const float4 kv = krow[(h * 8 + d4) ^ swz];
      a = fmaf(qv[d4].x, kv.x, a);
      a = fmaf(qv[d4].y, kv.y, a);
      a = fmaf(qv[d4].z, kv.z, a);
      a = fmaf(qv[d4].w, kv.w, a);
    }
    s[c] = a + bb[c * 32 + il];
  }

  // softmax over 128 values (4 regs x 32 lanes of this head group)
  float m = fmaxf(fmaxf(s[0], s[1]), fmaxf(s[2], s[3]));
#pragma unroll
  for (int off = 16; off >= 1; off >>= 1) m = fmaxf(m, __shfl_xor(m, off));
  float e[4];
  float sum = 0.f;
#pragma unroll
  for (int r = 0; r < 4; ++r) { e[r] = __expf(s[r] - m); sum += e[r]; }
#pragma unroll
  for (int off = 16; off >= 1; off >>= 1) sum += __shfl_xor(sum, off);
  const float inv = 1.f / sum;
#pragma unroll
  for (int r = 0; r < 4; ++r) p[h][il + 32 * r] = e[r] * inv;
  __syncthreads();

  // PV: thread t -> (h, d). For fixed i the block reads the full vh row
  // coalesced; 4 independent accumulators break the FMA chain.
  const float* vb = vh + (size_t)f * NALL_ * CH_ + h * D_ + il;
  float ac0 = 0.f, ac1 = 0.f, ac2 = 0.f, ac3 = 0.f;
  for (int i = 0; i < NNEI_; i += 4) {
    const float4 p4 = *(const float4*)(&p[h][i]);
    const int4  j4 = *(const int4*)(&jn[i]);
    ac0 = fmaf(p4.x, vb[(size_t)j4.x * CH_], ac0);
    ac1 = fmaf(p4.y, vb[(size_t)j4.y * CH_], ac1);
    ac2 = fmaf(p4.z, vb[(size_t)j4.z * CH_], ac2);
    ac3 = fmaf(p4.w, vb[(size_t)j4.w * CH_], ac3);
  }
  const float acc = (ac0 + ac1) + (ac2 + ac3);

  const float g = gs[row * CH_ + t];
  x[row * CH_ + t] = g * acc;
}

// ---------------------------------------------------------------------------
extern "C" void kernel_launch(void* const* d_in, const int* in_sizes, int n_in,
                              void* d_out, int out_size, void* d_ws, size_t ws_size,
                              hipStream_t stream) {
  const float* q     = (const float*)d_in[0];
  const float* k     = (const float*)d_in[1];
  const float* v     = (const float*)d_in[2];
  const void*  nlist = d_in[3];
  const float* bias  = (const float*)d_in[4];
  const float* Wq    = (const float*)d_in[5];
  const float* Wk    = (const float*)d_in[6];
  const float* Wv    = (const float*)d_in[7];
  const float* Wg    = (const float*)d_in[8];
  const float* bg    = (const float*)d_in[9];
  const float* Wo    = (const float*)d_in[10];
  const float* bo    = (const float*)d_in[11];
  float* out = (float*)d_out;

  float* ws = (float*)d_ws;
  float* qh = ws;                                   // [4096,256]
  float* gs = qh + (size_t)NF_ * NLOC_ * CH_;       // [4096,256]
  float* kh = gs + (size_t)NF_ * NLOC_ * CH_;       // [6144,256]
  float* vh = kh + (size_t)NF_ * NALL_ * CH_;       // [6144,256]
  float* x  = vh + (size_t)NF_ * NALL_ * CH_;       // [4096,256]
  unsigned short* whl = (unsigned short*)(x + (size_t)NF_ * NLOC_ * CH_);
                                                    // [5][2][65536] bf16

  // one-time weight split: order matches proj blockIdx.z {Wq,Wg,Wk,Wv}, then Wo
  wcvt_kernel<<<dim3(64, 5), 256, 0, stream>>>(Wq, Wg, Wk, Wv, Wo, whl);
  // projections: z = {qh, gate, kh, vh}; 128x64 MFMA tiles
  proj_kernel<<<dim3(4, 48, 4), 256, 0, stream>>>(q, k, v, whl, bg,
                                                  qh, gs, kh, vh);
  // attention + gating
  attn_kernel<<<dim3(NF_ * NLOC_), 256, 0, stream>>>(qh, gs, kh, vh, nlist, bias, x);
  // output projection
  out_gemm_kernel<<<dim3(4, 32), 256, 0, stream>>>(x, whl, bo, out);
}